// Round 4
// baseline (189.638 us; speedup 1.0000x reference)
//
#include <hip/hip_runtime.h>
#include <cstdint>
#include <cstddef>

// ---------------- problem constants ----------------
#define Bn   16
#define Cn   256
#define Nn   4096      // 16^3 spatial
#define Ln   77
#define LPn  80        // padded L rows for k_t (scores N-dim, 5 tiles of 16)
#define LKn  96        // padded L for PV K-dim (3 k-steps of 32)
#define CTXn 768
#define Gn   32

typedef unsigned short u16;
typedef unsigned int   u32;
using frag8 = __attribute__((ext_vector_type(8))) short;   // 8 x bf16 (4 VGPR)
using f32x4 = __attribute__((ext_vector_type(4))) float;
using u16x4 = __attribute__((ext_vector_type(4))) u16;

__device__ __forceinline__ float b2f(u16 b) {
    union { u32 u; float f; } v; v.u = ((u32)b) << 16; return v.f;
}
__device__ __forceinline__ u16 f2b(float f) {  // RNE f32->bf16
    union { float f; u32 u; } v; v.f = f;
    u32 u = v.u;
    return (u16)((u + 0x7fffu + ((u >> 16) & 1u)) >> 16);
}
__device__ __forceinline__ u16x4 cast4(f32x4 s) {
    u16x4 p; p[0] = f2b(s[0]); p[1] = f2b(s[1]); p[2] = f2b(s[2]); p[3] = f2b(s[3]);
    return p;
}
// async global->LDS, 16B per lane. LDS dest must be lane-linear (base + lane*16).
__device__ __forceinline__ void gl16(const u16* g, u16* l) {
    __builtin_amdgcn_global_load_lds((const __attribute__((address_space(1))) u32*)g,
                                     (__attribute__((address_space(3))) u32*)l, 16, 0, 0);
}

// ---------------- ws layout (bytes) ----------------
static const size_t OFF_XT  = 0;
static const size_t OFF_HT  = 0;                    // alias: xt dead after qgemm
static const size_t OFF_Q   = 33554432;
static const size_t OFF_T   = 33554432;             // alias: q dead after attn
static const size_t OFF_CTXB = 33554432;            // bf16 [16][80][768] (dead before qgemm)
static const size_t OFF_KWB  = 35520512;            // bf16 [256][768]
static const size_t OFF_VWB  = 35913728;            // bf16 [256][768]
static const size_t OFF_KT  = 67108864;             // bf16 [B][80][256]
static const size_t OFF_V   = 67764224;             // bf16 [B][256][96]
static const size_t OFF_QWB = 68550656;             // bf16 [256][256]
static const size_t OFF_OWB = 68681728;             // bf16 [256][256]
static const size_t OFF_GS  = 68812800;             // f32 [B][32]
static const size_t OFF_GQ  = 68814848;             // f32 [B][32]

// ---------------- 1: cast everything to bf16 (vectorized, one pass) ----------------
__global__ void k_prep(const float* __restrict__ qw, const float* __restrict__ ow,
                       const float* __restrict__ kw, const float* __restrict__ vw,
                       const float* __restrict__ ctx,
                       u16* __restrict__ qwb, u16* __restrict__ owb,
                       u16* __restrict__ kwb, u16* __restrict__ vwb,
                       u16* __restrict__ ctxb) {
    int i = blockIdx.x * 256 + threadIdx.x;        // 376832 total
    if (i < 16384) {
        *(u16x4*)(qwb + i * 4) = cast4(*(const f32x4*)(qw + i * 4));
    } else if (i < 32768) {
        int j = i - 16384;
        *(u16x4*)(owb + j * 4) = cast4(*(const f32x4*)(ow + j * 4));
    } else if (i < 81920) {
        int j = i - 32768;
        *(u16x4*)(kwb + j * 4) = cast4(*(const f32x4*)(kw + j * 4));
    } else if (i < 131072) {
        int j = i - 81920;
        *(u16x4*)(vwb + j * 4) = cast4(*(const f32x4*)(vw + j * 4));
    } else {
        int j = i - 131072;                        // 0..245759
        int e = j * 4;
        int row = e / CTXn;                        // b*80 + l
        int d = e - row * CTXn;
        int b = row / LPn, l = row - b * LPn;
        u16x4 pk;
        if (l < Ln) {
            pk = cast4(*(const f32x4*)(ctx + ((size_t)(b * Ln + l)) * CTXn + d));
        } else {
            pk[0] = 0; pk[1] = 0; pk[2] = 0; pk[3] = 0;
        }
        *(u16x4*)(ctxb + e) = pk;
    }
}

// ---------------- 2: transpose+cast x[b][c][n] -> xt[b][n][c] ----------------
__global__ void k_xt(const float* __restrict__ x, u16* __restrict__ xt) {
    int b = blockIdx.z;
    int c0 = blockIdx.y * 64, n0 = blockIdx.x * 64;
    __shared__ float tile[64][65];   // +1 pad: conflict-free column reads
    int tid = threadIdx.x;
    int tr = tid >> 4, tc4 = (tid & 15) * 4;
#pragma unroll
    for (int i = 0; i < 4; ++i) {
        int cc = tr + i * 16;
        f32x4 vv = *(const f32x4*)(x + ((size_t)(b * Cn + c0 + cc)) * Nn + n0 + tc4);
#pragma unroll
        for (int j = 0; j < 4; ++j) tile[cc][tc4 + j] = vv[j];
    }
    __syncthreads();
#pragma unroll
    for (int i = 0; i < 4; ++i) {
        int nn = tr + i * 16;
        u16x4 pk;
#pragma unroll
        for (int j = 0; j < 4; ++j) pk[j] = f2b(tile[tc4 + j][nn]);
        *(u16x4*)(xt + ((size_t)(b * Nn + n0 + nn)) * Cn + c0 + tc4) = pk;
    }
}

// ---------------- 3: k/v projections via MFMA ----------------
__launch_bounds__(256)
__global__ void k_kv(const u16* __restrict__ kwb, const u16* __restrict__ vwb,
                     const u16* __restrict__ ctxb, u16* __restrict__ kt,
                     u16* __restrict__ v) {
    int b = blockIdx.y;
    int tid = threadIdx.x;
    int wave = tid >> 6, lane = tid & 63;
    int l15 = lane & 15, q4 = lane >> 4;
    int c0 = blockIdx.x * 64 + wave * 16;
    const u16* cb = ctxb + (size_t)b * LPn * CTXn;

    f32x4 ak[5], av[5];
#pragma unroll
    for (int lt = 0; lt < 5; ++lt) {
        ak[lt] = (f32x4){0.f, 0.f, 0.f, 0.f};
        av[lt] = (f32x4){0.f, 0.f, 0.f, 0.f};
    }
    for (int ks = 0; ks < CTXn / 32; ++ks) {
        int kk = ks * 32 + 8 * q4;
        frag8 fk = *(const frag8*)(kwb + (size_t)(c0 + l15) * CTXn + kk);
        frag8 fv = *(const frag8*)(vwb + (size_t)(c0 + l15) * CTXn + kk);
#pragma unroll
        for (int lt = 0; lt < 5; ++lt) {
            frag8 fc = *(const frag8*)(cb + (size_t)(lt * 16 + l15) * CTXn + kk);
            ak[lt] = __builtin_amdgcn_mfma_f32_16x16x32_bf16(fk, fc, ak[lt], 0, 0, 0);
            av[lt] = __builtin_amdgcn_mfma_f32_16x16x32_bf16(fc, fv, av[lt], 0, 0, 0);
        }
    }
#pragma unroll
    for (int lt = 0; lt < 5; ++lt) {
        *(u16x4*)(kt + ((size_t)(b * LPn + lt * 16 + l15)) * Cn + c0 + q4 * 4) = cast4(ak[lt]);
        *(u16x4*)(v + ((size_t)(b * Cn + c0 + l15)) * LKn + lt * 16 + q4 * 4) = cast4(av[lt]);
    }
    u16x4 z; z[0] = 0; z[1] = 0; z[2] = 0; z[3] = 0;
    *(u16x4*)(v + ((size_t)(b * Cn + c0 + l15)) * LKn + 80 + q4 * 4) = z;
}

// ---------------- 4/6: register-resident-A streaming GEMM ----------------
// A [256][256] bf16 (k contiguous) lives in VGPRs (each wave: its 64-o slice).
// B [B][4096][256] streamed through double-buffered LDS (64n x 256k tiles,
// fragment-order layout: 16B-chunk index = (ks*4+q4)*64 + row -> conflict-free
// ds_read_b128). Block: 128 n (2 tiles), grid 32x16 = 512 blocks (2/CU).
// MODE 0: qt[n][o] = sum_c A[o][c]*B[n][c] + bias[o]
// MODE 1: t[o][n]  = sum_c A[o][c]*B[n][c] + bias[o] + x[o][n] (f32),
//         + fused GroupNorm partial sums (swapped operands: D row = n)
template<int MODE>
__launch_bounds__(256)
__global__ void k_gemm(const u16* __restrict__ A, const u16* __restrict__ Bm,
                       const float* __restrict__ bias, const float* __restrict__ xres,
                       u16* __restrict__ outp, float* __restrict__ gsum,
                       float* __restrict__ gsq) {
    int sb = blockIdx.x, b = blockIdx.y;
    int n0 = sb * 128;
    int tid = threadIdx.x;
    int wq = tid >> 6, lane = tid & 63;
    int l15 = lane & 15, q4 = lane >> 4;

    __shared__ __align__(16) u16 sB[2][64 * 256];   // 2 x 32KB

    const u16* Bb = Bm + ((size_t)b * Nn + n0) * Cn;

    auto stage = [&](int buf, int tt) {
#pragma unroll
        for (int j = 0; j < 8; ++j) {
            int c = j * 256 + tid;                  // 16B-chunk index, lane-linear dest
            int kc = c >> 6, row = c & 63;
            gl16(Bb + (size_t)(tt * 64 + row) * Cn + kc * 8, &sB[buf][c * 8]);
        }
    };

    stage(0, 0);

    // A fragments resident in registers: row = wq*64+mt*16+l15, k = ks*32+q4*8
    frag8 areg[4][8];
#pragma unroll
    for (int mt = 0; mt < 4; ++mt)
#pragma unroll
        for (int ks = 0; ks < 8; ++ks)
            areg[mt][ks] = *(const frag8*)(A + (size_t)(wq * 64 + mt * 16 + l15) * Cn + ks * 32 + q4 * 8);

    f32x4 qb4[4];
    float obias[4], gps[4], gpq[4];
#pragma unroll
    for (int mt = 0; mt < 4; ++mt) {
        if (MODE == 0) {
            qb4[mt] = *(const f32x4*)(bias + wq * 64 + mt * 16 + q4 * 4);
        } else {
            obias[mt] = bias[wq * 64 + mt * 16 + l15];
            gps[mt] = 0.f; gpq[mt] = 0.f;
        }
    }

    __syncthreads();
    int buf = 0;
    for (int tt = 0; tt < 2; ++tt) {
        if (tt + 1 < 2) stage(buf ^ 1, tt + 1);
        f32x4 acc[4][4];
#pragma unroll
        for (int i = 0; i < 4; ++i)
#pragma unroll
            for (int j = 0; j < 4; ++j) acc[i][j] = (f32x4){0.f, 0.f, 0.f, 0.f};

#pragma unroll
        for (int ks = 0; ks < 8; ++ks) {
            frag8 bf[4];
#pragma unroll
            for (int nt = 0; nt < 4; ++nt)
                bf[nt] = *(const frag8*)&sB[buf][(size_t)(((ks * 4 + q4) * 64) + nt * 16 + l15) * 8];
            if (MODE == 0) {
#pragma unroll
                for (int mt = 0; mt < 4; ++mt)
#pragma unroll
                    for (int nt = 0; nt < 4; ++nt)
                        acc[mt][nt] = __builtin_amdgcn_mfma_f32_16x16x32_bf16(areg[mt][ks], bf[nt], acc[mt][nt], 0, 0, 0);
            } else {
#pragma unroll
                for (int nt = 0; nt < 4; ++nt)
#pragma unroll
                    for (int mt = 0; mt < 4; ++mt)
                        acc[nt][mt] = __builtin_amdgcn_mfma_f32_16x16x32_bf16(bf[nt], areg[mt][ks], acc[nt][mt], 0, 0, 0);
            }
        }

        if (MODE == 0) {
            // D row = o (q4*4+r), col = n (l15): store qt[n][o], 8B contiguous in o
            u16* qb_ = outp + (size_t)b * Nn * Cn;
#pragma unroll
            for (int mt = 0; mt < 4; ++mt) {
                int o4 = wq * 64 + mt * 16 + q4 * 4;
#pragma unroll
                for (int nt = 0; nt < 4; ++nt) {
                    int n = n0 + tt * 64 + nt * 16 + l15;
                    u16x4 pk;
#pragma unroll
                    for (int r = 0; r < 4; ++r) pk[r] = f2b(acc[mt][nt][r] + qb4[mt][r]);
                    *(u16x4*)(qb_ + (size_t)n * Cn + o4) = pk;
                }
            }
        } else {
            // D row = n (q4*4+r), col = o (l15): store t[o][n], 8B contiguous in n
#pragma unroll
            for (int mt = 0; mt < 4; ++mt) {
                int o = wq * 64 + mt * 16 + l15;
#pragma unroll
                for (int nt = 0; nt < 4; ++nt) {
                    int nb4 = n0 + tt * 64 + nt * 16 + q4 * 4;
                    size_t rowb = ((size_t)(b * Cn + o)) * Nn + nb4;
                    f32x4 xv = *(const f32x4*)(xres + rowb);
                    u16x4 pk;
#pragma unroll
                    for (int r = 0; r < 4; ++r) {
                        float val = acc[nt][mt][r] + obias[mt] + xv[r];
                        pk[r] = f2b(val);
                        gps[mt] += val; gpq[mt] += val * val;
                    }
                    *(u16x4*)(outp + rowb) = pk;
                }
            }
        }
        __syncthreads();
        buf ^= 1;
    }

    if (MODE == 1) {
        // reduce GroupNorm partials: merge l15&7 (xor 1,2,4) and q4 (xor 16,32)
#pragma unroll
        for (int mt = 0; mt < 4; ++mt) {
            float s = gps[mt], q = gpq[mt];
            s += __shfl_xor(s, 1);  q += __shfl_xor(q, 1);
            s += __shfl_xor(s, 2);  q += __shfl_xor(q, 2);
            s += __shfl_xor(s, 4);  q += __shfl_xor(q, 4);
            s += __shfl_xor(s, 16); q += __shfl_xor(q, 16);
            s += __shfl_xor(s, 32); q += __shfl_xor(q, 32);
            if ((lane & 55) == 0) {   // lane 0 or 8
                int g = (wq * 64 + mt * 16 + (lane & 8)) >> 3;
                atomicAdd(&gsum[b * Gn + g], s);
                atomicAdd(&gsq[b * Gn + g], q);
            }
        }
    }
}

// ---------------- 5: fused attention (1 wave / block, NT=16 rows) ----------------
__launch_bounds__(64)
__global__ void k_attn(const u16* __restrict__ kt, const u16* __restrict__ v,
                       const u16* __restrict__ qt, u16* __restrict__ ht) {
    int nb = blockIdx.x, b = blockIdx.y;
    int lane = threadIdx.x;
    int l15 = lane & 15, q4 = lane >> 4;
    const u16* ktb = kt + (size_t)b * LPn * Cn;
    const u16* qtb = qt + ((size_t)(b * Nn + nb * 16)) * Cn;

    f32x4 s[5];
#pragma unroll
    for (int mt = 0; mt < 5; ++mt) s[mt] = (f32x4){0.f, 0.f, 0.f, 0.f};
#pragma unroll
    for (int ks = 0; ks < 8; ++ks) {
        int kk = ks * 32 + 8 * q4;
        frag8 bq = *(const frag8*)(qtb + (size_t)l15 * Cn + kk);
#pragma unroll
        for (int mt = 0; mt < 5; ++mt) {
            frag8 ak = *(const frag8*)(ktb + (size_t)(mt * 16 + l15) * Cn + kk);
            s[mt] = __builtin_amdgcn_mfma_f32_16x16x32_bf16(ak, bq, s[mt], 0, 0, 0);
        }
    }
    float m = -3e38f;
#pragma unroll
    for (int mt = 0; mt < 5; ++mt)
#pragma unroll
        for (int r = 0; r < 4; ++r) {
            int l = mt * 16 + q4 * 4 + r;
            if (l < Ln) m = fmaxf(m, s[mt][r]);
        }
    m = fmaxf(m, __shfl_xor(m, 16));
    m = fmaxf(m, __shfl_xor(m, 32));
    float p[5][4];
    float sum = 0.f;
#pragma unroll
    for (int mt = 0; mt < 5; ++mt)
#pragma unroll
        for (int r = 0; r < 4; ++r) {
            int l = mt * 16 + q4 * 4 + r;
            float e = (l < Ln) ? __expf(s[mt][r] - m) : 0.f;
            p[mt][r] = e;
            sum += e;
        }
    sum += __shfl_xor(sum, 16);
    sum += __shfl_xor(sum, 32);
    float inv = 1.f / sum;

    __shared__ u16 w_lds[16][104];
    u32* wz = (u32*)&w_lds[0][0];
#pragma unroll
    for (int i = 0; i < 13; ++i) wz[lane + i * 64] = 0;
    __syncthreads();
#pragma unroll
    for (int mt = 0; mt < 5; ++mt)
#pragma unroll
        for (int r = 0; r < 4; ++r) {
            int l = mt * 16 + q4 * 4 + r;
            if (l < Ln) w_lds[l15][l] = f2b(p[mt][r] * inv);
        }
    __syncthreads();

    frag8 aw[3];
#pragma unroll
    for (int ks = 0; ks < 3; ++ks)
        aw[ks] = *(const frag8*)(&w_lds[l15][ks * 32 + 8 * q4]);
    const u16* vb = v + (size_t)b * Cn * LKn;
    u16* hb = ht + ((size_t)(b * Nn + nb * 16)) * Cn;
#pragma unroll
    for (int ct = 0; ct < 16; ++ct) {
        f32x4 h = (f32x4){0.f, 0.f, 0.f, 0.f};
#pragma unroll
        for (int ks = 0; ks < 3; ++ks) {
            frag8 bv = *(const frag8*)(vb + (size_t)(ct * 16 + l15) * LKn + ks * 32 + 8 * q4);
            h = __builtin_amdgcn_mfma_f32_16x16x32_bf16(aw[ks], bv, h, 0, 0, 0);
        }
#pragma unroll
        for (int r = 0; r < 4; ++r)
            hb[(size_t)(q4 * 4 + r) * Cn + ct * 16 + l15] = f2b(h[r]);
    }
}

// ---------------- 8: GroupNorm apply + Swish ----------------
__global__ void k_gnapply(const u16* __restrict__ t, const float* __restrict__ gsum,
                          const float* __restrict__ gsq, const float* __restrict__ gamma,
                          const float* __restrict__ beta, float* __restrict__ out) {
    int i = (blockIdx.x * 256 + threadIdx.x) * 4;
    int b = i >> 20;
    int rem = i & 1048575;
    int c = rem >> 12;
    int g = c >> 3;
    float mean = gsum[b * Gn + g] * (1.0f / 32768.f);
    float var = gsq[b * Gn + g] * (1.0f / 32768.f) - mean * mean;
    float rstd = rsqrtf(var + 1e-5f);
    float ga = gamma[c], be = beta[c];
    u16x4 tv = *(const u16x4*)(t + i);
    f32x4 o;
#pragma unroll
    for (int j = 0; j < 4; ++j) {
        float hv = (b2f(tv[j]) - mean) * rstd * ga + be;
        o[j] = hv / (1.f + __expf(-hv));
    }
    *(f32x4*)(out + i) = o;
}

// ---------------- launcher ----------------
extern "C" void kernel_launch(void* const* d_in, const int* in_sizes, int n_in,
                              void* d_out, int out_size, void* d_ws, size_t ws_size,
                              hipStream_t stream) {
    (void)in_sizes; (void)n_in; (void)out_size; (void)ws_size;
    const float* x     = (const float*)d_in[0];
    const float* ctx   = (const float*)d_in[1];
    const float* qw    = (const float*)d_in[2];
    const float* qb    = (const float*)d_in[3];
    const float* kw    = (const float*)d_in[4];
    const float* vw    = (const float*)d_in[5];
    const float* ow    = (const float*)d_in[6];
    const float* ob    = (const float*)d_in[7];
    const float* gamma = (const float*)d_in[8];
    const float* beta  = (const float*)d_in[9];
    float* out = (float*)d_out;
    char* ws = (char*)d_ws;

    u16* xt  = (u16*)(ws + OFF_XT);
    u16* ht  = (u16*)(ws + OFF_HT);
    u16* qt  = (u16*)(ws + OFF_Q);
    u16* t   = (u16*)(ws + OFF_T);
    u16* ctxb = (u16*)(ws + OFF_CTXB);
    u16* kwb  = (u16*)(ws + OFF_KWB);
    u16* vwb  = (u16*)(ws + OFF_VWB);
    u16* kt  = (u16*)(ws + OFF_KT);
    u16* v   = (u16*)(ws + OFF_V);
    u16* qwb = (u16*)(ws + OFF_QWB);
    u16* owb = (u16*)(ws + OFF_OWB);
    float* gsum = (float*)(ws + OFF_GS);
    float* gsq  = (float*)(ws + OFF_GQ);

    hipMemsetAsync(ws + OFF_GS, 0, 4096, stream);   // gsum+gsq

    k_prep<<<1472, 256, 0, stream>>>(qw, ow, kw, vw, ctx, qwb, owb, kwb, vwb, ctxb);
    k_xt<<<dim3(64, 4, 16), 256, 0, stream>>>(x, xt);
    k_kv<<<dim3(4, Bn), 256, 0, stream>>>(kwb, vwb, ctxb, kt, v);
    k_gemm<0><<<dim3(32, Bn), 256, 0, stream>>>(qwb, xt, qb, nullptr, qt, nullptr, nullptr);
    k_attn<<<dim3(256, Bn), 64, 0, stream>>>(kt, v, qt, ht);
    k_gemm<1><<<dim3(32, Bn), 256, 0, stream>>>(owb, ht, ob, x, t, gsum, gsq);
    k_gnapply<<<16384, 256, 0, stream>>>(t, gsum, gsq, gamma, beta, out);
}

// Round 5
// 183.555 us; speedup vs baseline: 1.0331x; 1.0331x over previous
//
#include <hip/hip_runtime.h>
#include <cstdint>
#include <cstddef>

// ---------------- problem constants ----------------
#define Bn   16
#define Cn   256
#define Nn   4096      // 16^3 spatial
#define Ln   77
#define LPn  80        // padded L rows for k_t
#define LKn  96        // padded L for PV K-dim
#define CTXn 768
#define Gn   32

typedef unsigned short u16;
typedef unsigned int   u32;
using frag8 = __attribute__((ext_vector_type(8))) short;   // 8 x bf16 (4 VGPR)
using u16x8 = __attribute__((ext_vector_type(8))) u16;
using f32x4 = __attribute__((ext_vector_type(4))) float;
using u16x4 = __attribute__((ext_vector_type(4))) u16;

__device__ __forceinline__ float b2f(u16 b) {
    union { u32 u; float f; } v; v.u = ((u32)b) << 16; return v.f;
}
__device__ __forceinline__ u16 f2b(float f) {  // RNE f32->bf16
    union { float f; u32 u; } v; v.f = f;
    u32 u = v.u;
    return (u16)((u + 0x7fffu + ((u >> 16) & 1u)) >> 16);
}
__device__ __forceinline__ u16x4 cast4(f32x4 s) {
    u16x4 p; p[0] = f2b(s[0]); p[1] = f2b(s[1]); p[2] = f2b(s[2]); p[3] = f2b(s[3]);
    return p;
}
// async global->LDS, 16B per lane. LDS dest must be lane-linear (base + lane*16).
__device__ __forceinline__ void gl16(const u16* g, u16* l) {
    __builtin_amdgcn_global_load_lds((const __attribute__((address_space(1))) u32*)g,
                                     (__attribute__((address_space(3))) u32*)l, 16, 0, 0);
}

// Chunked activation layout: [b][ntile(64)][kc(32)][row(64)] of 16B chunks (8 ch).
// u16 index = (((b*64 + nt)*2048) + kc*64 + row)*8 + (c&7),  kc = c>>3, row = n&63.
// Chunked weight layout: [kc(32)][row(256)] chunks: u16 idx = ((k>>3)*256 + r)*8 + (k&7).

// ---------------- ws layout (bytes) ----------------
static const size_t OFF_XT  = 0;
static const size_t OFF_HT  = 0;                    // alias: xt dead after gemm0
static const size_t OFF_Q   = 33554432;
static const size_t OFF_T   = 33554432;             // alias: q dead after attn
static const size_t OFF_CTXB = 33554432;            // bf16 [16][80][768] (dead before gemm0)
static const size_t OFF_KWB  = 35520512;            // bf16 [256][768]
static const size_t OFF_VWB  = 35913728;            // bf16 [256][768]
static const size_t OFF_KT  = 67108864;             // bf16 [B][80][256]
static const size_t OFF_V   = 67764224;             // bf16 [B][256][96]
static const size_t OFF_QWB = 68550656;             // bf16 chunked [32][256][8]
static const size_t OFF_OWB = 68681728;             // bf16 chunked [32][256][8]
static const size_t OFF_GS  = 68812800;             // f32 [B][32]
static const size_t OFF_GQ  = 68814848;             // f32 [B][32]

// ---------------- 1: cast to bf16 (qw/ow chunked; kw/vw/ctx row-major) ----------------
__global__ void k_prep(const float* __restrict__ qw, const float* __restrict__ ow,
                       const float* __restrict__ kw, const float* __restrict__ vw,
                       const float* __restrict__ ctx,
                       u16* __restrict__ qwb, u16* __restrict__ owb,
                       u16* __restrict__ kwb, u16* __restrict__ vwb,
                       u16* __restrict__ ctxb) {
    int i = blockIdx.x * 256 + threadIdx.x;        // 376832 total
    if (i < 16384) {
        int e = i * 4; int r = e >> 8; int k = e & 255;
        *(u16x4*)(qwb + ((size_t)((k >> 3) * 256 + r) * 8 + (k & 7))) =
            cast4(*(const f32x4*)(qw + e));
    } else if (i < 32768) {
        int e = (i - 16384) * 4; int r = e >> 8; int k = e & 255;
        *(u16x4*)(owb + ((size_t)((k >> 3) * 256 + r) * 8 + (k & 7))) =
            cast4(*(const f32x4*)(ow + e));
    } else if (i < 81920) {
        int j = i - 32768;
        *(u16x4*)(kwb + j * 4) = cast4(*(const f32x4*)(kw + j * 4));
    } else if (i < 131072) {
        int j = i - 81920;
        *(u16x4*)(vwb + j * 4) = cast4(*(const f32x4*)(vw + j * 4));
    } else {
        int j = i - 131072;                        // 0..245759
        int e = j * 4;
        int row = e / CTXn;                        // b*80 + l
        int d = e - row * CTXn;
        int b = row / LPn, l = row - b * LPn;
        u16x4 pk;
        if (l < Ln) {
            pk = cast4(*(const f32x4*)(ctx + ((size_t)(b * Ln + l)) * CTXn + d));
        } else {
            pk[0] = 0; pk[1] = 0; pk[2] = 0; pk[3] = 0;
        }
        *(u16x4*)(ctxb + e) = pk;
    }
}

// ---------------- 2: transpose+cast x[b][c][n] -> xt chunked ----------------
__global__ void k_xt(const float* __restrict__ x, u16* __restrict__ xt) {
    int b = blockIdx.z;
    int c0 = blockIdx.y * 64, nt = blockIdx.x;     // n0 = nt*64
    __shared__ float tile[64][65];   // [c][n], +1 pad
    int tid = threadIdx.x;
    int tr = tid >> 4, tc4 = (tid & 15) * 4;
#pragma unroll
    for (int i = 0; i < 4; ++i) {
        int cc = tr + i * 16;
        f32x4 vv = *(const f32x4*)(x + ((size_t)(b * Cn + c0 + cc)) * Nn + nt * 64 + tc4);
#pragma unroll
        for (int j = 0; j < 4; ++j) tile[cc][tc4 + j] = vv[j];
    }
    __syncthreads();
    int row = tid & 63, kq = tid >> 6;
    u16* xb = xt + ((size_t)(b * 64 + nt)) * 2048 * 8;
#pragma unroll
    for (int it = 0; it < 2; ++it) {
        int kcl = kq + it * 4;                     // local chunk 0..7
        u16x8 pk;
#pragma unroll
        for (int j = 0; j < 8; ++j) pk[j] = f2b(tile[kcl * 8 + j][row]);
        *(u16x8*)(xb + (size_t)(((c0 >> 3) + kcl) * 64 + row) * 8) = pk;
    }
}

// ---------------- 3: k/v projections via MFMA ----------------
__launch_bounds__(256)
__global__ void k_kv(const u16* __restrict__ kwb, const u16* __restrict__ vwb,
                     const u16* __restrict__ ctxb, u16* __restrict__ kt,
                     u16* __restrict__ v) {
    int b = blockIdx.y;
    int tid = threadIdx.x;
    int wave = tid >> 6, lane = tid & 63;
    int l15 = lane & 15, q4 = lane >> 4;
    int c0 = blockIdx.x * 64 + wave * 16;
    const u16* cb = ctxb + (size_t)b * LPn * CTXn;

    f32x4 ak[5], av[5];
#pragma unroll
    for (int lt = 0; lt < 5; ++lt) {
        ak[lt] = (f32x4){0.f, 0.f, 0.f, 0.f};
        av[lt] = (f32x4){0.f, 0.f, 0.f, 0.f};
    }
    for (int ks = 0; ks < CTXn / 32; ++ks) {
        int kk = ks * 32 + 8 * q4;
        frag8 fk = *(const frag8*)(kwb + (size_t)(c0 + l15) * CTXn + kk);
        frag8 fv = *(const frag8*)(vwb + (size_t)(c0 + l15) * CTXn + kk);
#pragma unroll
        for (int lt = 0; lt < 5; ++lt) {
            frag8 fc = *(const frag8*)(cb + (size_t)(lt * 16 + l15) * CTXn + kk);
            ak[lt] = __builtin_amdgcn_mfma_f32_16x16x32_bf16(fk, fc, ak[lt], 0, 0, 0);
            av[lt] = __builtin_amdgcn_mfma_f32_16x16x32_bf16(fc, fv, av[lt], 0, 0, 0);
        }
    }
#pragma unroll
    for (int lt = 0; lt < 5; ++lt) {
        *(u16x4*)(kt + ((size_t)(b * LPn + lt * 16 + l15)) * Cn + c0 + q4 * 4) = cast4(ak[lt]);
        *(u16x4*)(v + ((size_t)(b * Cn + c0 + l15)) * LKn + lt * 16 + q4 * 4) = cast4(av[lt]);
    }
    u16x4 z; z[0] = 0; z[1] = 0; z[2] = 0; z[3] = 0;
    *(u16x4*)(v + ((size_t)(b * Cn + c0 + l15)) * LKn + 80 + q4 * 4) = z;
}

// ---------------- 4/6: register-A streaming GEMM, chunked layouts ----------------
// A chunked [kc(32)][row(256)] in VGPRs (wave: 64-o slice). B chunked per 64n tile,
// staged via fully-coalesced gl16 into 32KB LDS (chunk c -> sB[c*8], conflict-free
// ds_read). Grid (64, B) = 1024 blocks, 1 tile/block, 1 barrier/block.
// MODE 0: qt(chunked)[n][o] = sum_c A[o][c]*B[n][c] + bias[o]
// MODE 1: t[o][n] = sum + bias[o] + x[o][n] (f32), + fused GN partials (D row = n)
template<int MODE>
__launch_bounds__(256)
__global__ void k_gemm(const u16* __restrict__ A, const u16* __restrict__ Bm,
                       const float* __restrict__ bias, const float* __restrict__ xres,
                       u16* __restrict__ outp, float* __restrict__ gsum,
                       float* __restrict__ gsq) {
    int T = blockIdx.x, b = blockIdx.y;
    int tid = threadIdx.x;
    int wq = tid >> 6, lane = tid & 63;
    int l15 = lane & 15, q4 = lane >> 4;

    __shared__ __align__(16) u16 sB[64 * 256];     // 32KB, chunk-ordered

    const u16* Bb = Bm + ((size_t)(b * 64 + T)) * 2048 * 8;
#pragma unroll
    for (int j = 0; j < 8; ++j) {
        int c = j * 256 + tid;                     // chunk idx: linear in lane, both sides
        gl16(Bb + (size_t)c * 8, &sB[c * 8]);
    }

    // A fragments resident: row = wq*64+mt*16+l15, kc = ks*4+q4 (coalesced chunks)
    frag8 areg[4][8];
#pragma unroll
    for (int mt = 0; mt < 4; ++mt)
#pragma unroll
        for (int ks = 0; ks < 8; ++ks)
            areg[mt][ks] = *(const frag8*)(A + (size_t)((ks * 4 + q4) * 256 + wq * 64 + mt * 16 + l15) * 8);

    f32x4 qb4[4];
    float obias[4], gps[4], gpq[4];
#pragma unroll
    for (int mt = 0; mt < 4; ++mt) {
        if (MODE == 0) {
            qb4[mt] = *(const f32x4*)(bias + wq * 64 + mt * 16 + q4 * 4);
        } else {
            obias[mt] = bias[wq * 64 + mt * 16 + l15];
            gps[mt] = 0.f; gpq[mt] = 0.f;
        }
    }

    f32x4 acc[4][4];
#pragma unroll
    for (int i = 0; i < 4; ++i)
#pragma unroll
        for (int j = 0; j < 4; ++j) acc[i][j] = (f32x4){0.f, 0.f, 0.f, 0.f};

    __syncthreads();

#pragma unroll
    for (int ks = 0; ks < 8; ++ks) {
        frag8 bf[4];
#pragma unroll
        for (int nt = 0; nt < 4; ++nt)
            bf[nt] = *(const frag8*)&sB[(size_t)((ks * 4 + q4) * 64 + nt * 16 + l15) * 8];
        if (MODE == 0) {
#pragma unroll
            for (int mt = 0; mt < 4; ++mt)
#pragma unroll
                for (int nt = 0; nt < 4; ++nt)
                    acc[mt][nt] = __builtin_amdgcn_mfma_f32_16x16x32_bf16(areg[mt][ks], bf[nt], acc[mt][nt], 0, 0, 0);
        } else {
#pragma unroll
            for (int nt = 0; nt < 4; ++nt)
#pragma unroll
                for (int mt = 0; mt < 4; ++mt)
                    acc[nt][mt] = __builtin_amdgcn_mfma_f32_16x16x32_bf16(bf[nt], areg[mt][ks], acc[nt][mt], 0, 0, 0);
        }
    }

    if (MODE == 0) {
        // D row = o (q4*4+r), col = n (l15). Store chunked qt: coalesced 8B pieces.
        u16* qb_ = outp + ((size_t)(b * 64 + T)) * 2048 * 8;
#pragma unroll
        for (int mt = 0; mt < 4; ++mt) {
            int o4 = wq * 64 + mt * 16 + q4 * 4;
#pragma unroll
            for (int nt = 0; nt < 4; ++nt) {
                int row = nt * 16 + l15;
                u16x4 pk;
#pragma unroll
                for (int r = 0; r < 4; ++r) pk[r] = f2b(acc[mt][nt][r] + qb4[mt][r]);
                *(u16x4*)(qb_ + (size_t)((o4 >> 3) * 64 + row) * 8 + (o4 & 7)) = pk;
            }
        }
    } else {
        // D row = n (q4*4+r), col = o (l15). Store t[o][n] + residual + GN partials.
#pragma unroll
        for (int mt = 0; mt < 4; ++mt) {
            int o = wq * 64 + mt * 16 + l15;
#pragma unroll
            for (int nt = 0; nt < 4; ++nt) {
                int nb4 = T * 64 + nt * 16 + q4 * 4;
                size_t rowb = ((size_t)(b * Cn + o)) * Nn + nb4;
                f32x4 xv = *(const f32x4*)(xres + rowb);
                u16x4 pk;
#pragma unroll
                for (int r = 0; r < 4; ++r) {
                    float val = acc[nt][mt][r] + obias[mt] + xv[r];
                    pk[r] = f2b(val);
                    gps[mt] += val; gpq[mt] += val * val;
                }
                *(u16x4*)(outp + rowb) = pk;
            }
        }
#pragma unroll
        for (int mt = 0; mt < 4; ++mt) {
            float s = gps[mt], q = gpq[mt];
            s += __shfl_xor(s, 1);  q += __shfl_xor(q, 1);
            s += __shfl_xor(s, 2);  q += __shfl_xor(q, 2);
            s += __shfl_xor(s, 4);  q += __shfl_xor(q, 4);
            s += __shfl_xor(s, 16); q += __shfl_xor(q, 16);
            s += __shfl_xor(s, 32); q += __shfl_xor(q, 32);
            if ((lane & 55) == 0) {   // lane 0 or 8
                int g = (wq * 64 + mt * 16 + (lane & 8)) >> 3;
                atomicAdd(&gsum[b * Gn + g], s);
                atomicAdd(&gsq[b * Gn + g], q);
            }
        }
    }
}

// ---------------- 5: fused attention (1 wave / block, 16 n-rows) ----------------
__launch_bounds__(64)
__global__ void k_attn(const u16* __restrict__ kt, const u16* __restrict__ v,
                       const u16* __restrict__ qt, u16* __restrict__ ht) {
    int nb = blockIdx.x, b = blockIdx.y;
    int lane = threadIdx.x;
    int l15 = lane & 15, q4 = lane >> 4;
    const u16* ktb = kt + (size_t)b * LPn * Cn;
    // chunked qt: tile = nb>>2, rows (nb&3)*16 .. +16
    const u16* qtb = qt + (((size_t)(b * 64 + (nb >> 2))) * 2048 + (nb & 3) * 16) * 8;

    f32x4 s[5];
#pragma unroll
    for (int mt = 0; mt < 5; ++mt) s[mt] = (f32x4){0.f, 0.f, 0.f, 0.f};
#pragma unroll
    for (int ks = 0; ks < 8; ++ks) {
        int kk = ks * 32 + 8 * q4;
        frag8 bq = *(const frag8*)(qtb + (size_t)((ks * 4 + q4) * 64 + l15) * 8);
#pragma unroll
        for (int mt = 0; mt < 5; ++mt) {
            frag8 ak = *(const frag8*)(ktb + (size_t)(mt * 16 + l15) * Cn + kk);
            s[mt] = __builtin_amdgcn_mfma_f32_16x16x32_bf16(ak, bq, s[mt], 0, 0, 0);
        }
    }
    float m = -3e38f;
#pragma unroll
    for (int mt = 0; mt < 5; ++mt)
#pragma unroll
        for (int r = 0; r < 4; ++r) {
            int l = mt * 16 + q4 * 4 + r;
            if (l < Ln) m = fmaxf(m, s[mt][r]);
        }
    m = fmaxf(m, __shfl_xor(m, 16));
    m = fmaxf(m, __shfl_xor(m, 32));
    float p[5][4];
    float sum = 0.f;
#pragma unroll
    for (int mt = 0; mt < 5; ++mt)
#pragma unroll
        for (int r = 0; r < 4; ++r) {
            int l = mt * 16 + q4 * 4 + r;
            float e = (l < Ln) ? __expf(s[mt][r] - m) : 0.f;
            p[mt][r] = e;
            sum += e;
        }
    sum += __shfl_xor(sum, 16);
    sum += __shfl_xor(sum, 32);
    float inv = 1.f / sum;

    __shared__ u16 w_lds[16][104];
    u32* wz = (u32*)&w_lds[0][0];
#pragma unroll
    for (int i = 0; i < 13; ++i) wz[lane + i * 64] = 0;
    __syncthreads();
#pragma unroll
    for (int mt = 0; mt < 5; ++mt)
#pragma unroll
        for (int r = 0; r < 4; ++r) {
            int l = mt * 16 + q4 * 4 + r;
            if (l < Ln) w_lds[l15][l] = f2b(p[mt][r] * inv);
        }
    __syncthreads();

    frag8 aw[3];
#pragma unroll
    for (int ks = 0; ks < 3; ++ks)
        aw[ks] = *(const frag8*)(&w_lds[l15][ks * 32 + 8 * q4]);
    const u16* vb = v + (size_t)b * Cn * LKn;
    // chunked ht: tile = nb>>2, rows (nb&3)*16 .. +16
    u16* hb = ht + (((size_t)(b * 64 + (nb >> 2))) * 2048 + (nb & 3) * 16) * 8;
#pragma unroll
    for (int ct = 0; ct < 16; ++ct) {
        f32x4 h = (f32x4){0.f, 0.f, 0.f, 0.f};
#pragma unroll
        for (int ks = 0; ks < 3; ++ks) {
            frag8 bv = *(const frag8*)(vb + (size_t)(ct * 16 + l15) * LKn + ks * 32 + 8 * q4);
            h = __builtin_amdgcn_mfma_f32_16x16x32_bf16(aw[ks], bv, h, 0, 0, 0);
        }
        int kc = ct * 2 + (l15 >> 3), off = l15 & 7;
#pragma unroll
        for (int r = 0; r < 4; ++r)
            hb[(size_t)(kc * 64 + q4 * 4 + r) * 8 + off] = f2b(h[r]);
    }
}

// ---------------- 8: GroupNorm apply + Swish ----------------
__global__ void k_gnapply(const u16* __restrict__ t, const float* __restrict__ gsum,
                          const float* __restrict__ gsq, const float* __restrict__ gamma,
                          const float* __restrict__ beta, float* __restrict__ out) {
    int i = (blockIdx.x * 256 + threadIdx.x) * 4;
    int b = i >> 20;
    int rem = i & 1048575;
    int c = rem >> 12;
    int g = c >> 3;
    float mean = gsum[b * Gn + g] * (1.0f / 32768.f);
    float var = gsq[b * Gn + g] * (1.0f / 32768.f) - mean * mean;
    float rstd = rsqrtf(var + 1e-5f);
    float ga = gamma[c], be = beta[c];
    u16x4 tv = *(const u16x4*)(t + i);
    f32x4 o;
#pragma unroll
    for (int j = 0; j < 4; ++j) {
        float hv = (b2f(tv[j]) - mean) * rstd * ga + be;
        o[j] = hv / (1.f + __expf(-hv));
    }
    *(f32x4*)(out + i) = o;
}

// ---------------- launcher ----------------
extern "C" void kernel_launch(void* const* d_in, const int* in_sizes, int n_in,
                              void* d_out, int out_size, void* d_ws, size_t ws_size,
                              hipStream_t stream) {
    (void)in_sizes; (void)n_in; (void)out_size; (void)ws_size;
    const float* x     = (const float*)d_in[0];
    const float* ctx   = (const float*)d_in[1];
    const float* qw    = (const float*)d_in[2];
    const float* qb    = (const float*)d_in[3];
    const float* kw    = (const float*)d_in[4];
    const float* vw    = (const float*)d_in[5];
    const float* ow    = (const float*)d_in[6];
    const float* ob    = (const float*)d_in[7];
    const float* gamma = (const float*)d_in[8];
    const float* beta  = (const float*)d_in[9];
    float* out = (float*)d_out;
    char* ws = (char*)d_ws;

    u16* xt  = (u16*)(ws + OFF_XT);
    u16* ht  = (u16*)(ws + OFF_HT);
    u16* qt  = (u16*)(ws + OFF_Q);
    u16* t   = (u16*)(ws + OFF_T);
    u16* ctxb = (u16*)(ws + OFF_CTXB);
    u16* kwb  = (u16*)(ws + OFF_KWB);
    u16* vwb  = (u16*)(ws + OFF_VWB);
    u16* kt  = (u16*)(ws + OFF_KT);
    u16* v   = (u16*)(ws + OFF_V);
    u16* qwb = (u16*)(ws + OFF_QWB);
    u16* owb = (u16*)(ws + OFF_OWB);
    float* gsum = (float*)(ws + OFF_GS);
    float* gsq  = (float*)(ws + OFF_GQ);

    hipMemsetAsync(ws + OFF_GS, 0, 4096, stream);   // gsum+gsq

    k_prep<<<1472, 256, 0, stream>>>(qw, ow, kw, vw, ctx, qwb, owb, kwb, vwb, ctxb);
    k_xt<<<dim3(64, 4, 16), 256, 0, stream>>>(x, xt);
    k_kv<<<dim3(4, Bn), 256, 0, stream>>>(kwb, vwb, ctxb, kt, v);
    k_gemm<0><<<dim3(64, Bn), 256, 0, stream>>>(qwb, xt, qb, nullptr, qt, nullptr, nullptr);
    k_attn<<<dim3(256, Bn), 64, 0, stream>>>(kt, v, qt, ht);
    k_gemm<1><<<dim3(64, Bn), 256, 0, stream>>>(owb, ht, ob, x, t, gsum, gsq);
    k_gnapply<<<16384, 256, 0, stream>>>(t, gsum, gsq, gamma, beta, out);
}

// Round 6
// 142.667 us; speedup vs baseline: 1.3292x; 1.2866x over previous
//
#include <hip/hip_runtime.h>
#include <cstdint>
#include <cstddef>

// ---------------- problem constants ----------------
#define Bn   16
#define Cn   256
#define Nn   4096      // 16^3 spatial
#define Ln   77
#define LPn  80        // padded L rows (scores), 5 tiles of 16
#define LKn  96        // padded L for PV K-dim (3 k-steps of 32)
#define CTXn 768
#define Gn   32

typedef unsigned short u16;
typedef unsigned int   u32;
using frag8 = __attribute__((ext_vector_type(8))) short;   // 8 x bf16 (4 VGPR)
using f32x4 = __attribute__((ext_vector_type(4))) float;
using u16x4 = __attribute__((ext_vector_type(4))) u16;

__device__ __forceinline__ float b2f(u16 b) {
    union { u32 u; float f; } v; v.u = ((u32)b) << 16; return v.f;
}
__device__ __forceinline__ u16 f2b(float f) {  // RNE f32->bf16
    union { float f; u32 u; } v; v.f = f;
    u32 u = v.u;
    return (u16)((u + 0x7fffu + ((u >> 16) & 1u)) >> 16);
}
__device__ __forceinline__ u16x4 cast4(f32x4 s) {
    u16x4 p; p[0] = f2b(s[0]); p[1] = f2b(s[1]); p[2] = f2b(s[2]); p[3] = f2b(s[3]);
    return p;
}
// async global->LDS, 16B per lane. LDS dest must be lane-linear (base + lane*16).
__device__ __forceinline__ void gl16(const u16* g, u16* l) {
    __builtin_amdgcn_global_load_lds((const __attribute__((address_space(1))) u32*)g,
                                     (__attribute__((address_space(3))) u32*)l, 16, 0, 0);
}

// Chunked activation layout: [b][ntile(64)][kc(32)][row(64)] of 16B chunks (8 ch).
// u16 index = (((b*64+nt)*2048) + kc*64 + row)*8 + (c&7),  kc=c>>3, row=n&63.
// Chunked weight layout: [kc(32)][row(256)]: u16 idx = ((k>>3)*256 + r)*8 + (k&7).
// Chunked kt layout:     [b][kc(32)][l(80)]: u16 idx = b*20480 + ((c>>3)*80 + l)*8 + (c&7).

// ---------------- ws layout (bytes) ----------------
static const size_t OFF_HT  = 0;                    // bf16 chunked [B][64][2048][8]
static const size_t OFF_Q   = 33554432;             // bf16 chunked (qt), later t
static const size_t OFF_T   = 33554432;             // alias: qt dead after attn
static const size_t OFF_CTXB = 33554432;            // bf16 [16][80][768] (dead before gemm0)
static const size_t OFF_KWB  = 35520512;            // bf16 [256][768]
static const size_t OFF_VWB  = 35913728;            // bf16 [256][768]
static const size_t OFF_KT  = 67108864;             // bf16 chunked [B][32][80][8] (40KB/b)
static const size_t OFF_V   = 67764224;             // bf16 [B][256][96]
static const size_t OFF_QWB = 68550656;             // bf16 chunked [32][256][8]
static const size_t OFF_OWB = 68681728;             // bf16 chunked [32][256][8]
static const size_t OFF_GS  = 68812800;             // f32 [B][32]
static const size_t OFF_GQ  = 68814848;             // f32 [B][32]

// ---------------- 1: cast to bf16 (qw/ow chunked; kw/vw/ctx row-major) ----------------
__global__ void k_prep(const float* __restrict__ qw, const float* __restrict__ ow,
                       const float* __restrict__ kw, const float* __restrict__ vw,
                       const float* __restrict__ ctx,
                       u16* __restrict__ qwb, u16* __restrict__ owb,
                       u16* __restrict__ kwb, u16* __restrict__ vwb,
                       u16* __restrict__ ctxb) {
    int i = blockIdx.x * 256 + threadIdx.x;        // 376832 total
    if (i < 16384) {
        int e = i * 4; int r = e >> 8; int k = e & 255;
        *(u16x4*)(qwb + ((size_t)((k >> 3) * 256 + r) * 8 + (k & 7))) =
            cast4(*(const f32x4*)(qw + e));
    } else if (i < 32768) {
        int e = (i - 16384) * 4; int r = e >> 8; int k = e & 255;
        *(u16x4*)(owb + ((size_t)((k >> 3) * 256 + r) * 8 + (k & 7))) =
            cast4(*(const f32x4*)(ow + e));
    } else if (i < 81920) {
        int j = i - 32768;
        *(u16x4*)(kwb + j * 4) = cast4(*(const f32x4*)(kw + j * 4));
    } else if (i < 131072) {
        int j = i - 81920;
        *(u16x4*)(vwb + j * 4) = cast4(*(const f32x4*)(vw + j * 4));
    } else {
        int j = i - 131072;                        // 0..245759
        int e = j * 4;
        int row = e / CTXn;                        // b*80 + l
        int d = e - row * CTXn;
        int b = row / LPn, l = row - b * LPn;
        u16x4 pk;
        if (l < Ln) {
            pk = cast4(*(const f32x4*)(ctx + ((size_t)(b * Ln + l)) * CTXn + d));
        } else {
            pk[0] = 0; pk[1] = 0; pk[2] = 0; pk[3] = 0;
        }
        *(u16x4*)(ctxb + e) = pk;
    }
}

// ---------------- 2: k/v projections via MFMA (kt stored chunked) ----------------
__launch_bounds__(256)
__global__ void k_kv(const u16* __restrict__ kwb, const u16* __restrict__ vwb,
                     const u16* __restrict__ ctxb, u16* __restrict__ kt,
                     u16* __restrict__ v) {
    int b = blockIdx.y;
    int tid = threadIdx.x;
    int wave = tid >> 6, lane = tid & 63;
    int l15 = lane & 15, q4 = lane >> 4;
    int c0 = blockIdx.x * 64 + wave * 16;
    const u16* cb = ctxb + (size_t)b * LPn * CTXn;

    f32x4 ak[5], av[5];
#pragma unroll
    for (int lt = 0; lt < 5; ++lt) {
        ak[lt] = (f32x4){0.f, 0.f, 0.f, 0.f};
        av[lt] = (f32x4){0.f, 0.f, 0.f, 0.f};
    }
    for (int ks = 0; ks < CTXn / 32; ++ks) {
        int kk = ks * 32 + 8 * q4;
        frag8 fk = *(const frag8*)(kwb + (size_t)(c0 + l15) * CTXn + kk);
        frag8 fv = *(const frag8*)(vwb + (size_t)(c0 + l15) * CTXn + kk);
#pragma unroll
        for (int lt = 0; lt < 5; ++lt) {
            frag8 fc = *(const frag8*)(cb + (size_t)(lt * 16 + l15) * CTXn + kk);
            ak[lt] = __builtin_amdgcn_mfma_f32_16x16x32_bf16(fk, fc, ak[lt], 0, 0, 0);
            av[lt] = __builtin_amdgcn_mfma_f32_16x16x32_bf16(fc, fv, av[lt], 0, 0, 0);
        }
    }
    // kt chunked: D row = c (q4*4..+3), col = l (l15)
    int cc0 = c0 + q4 * 4;
    u16* ktb = kt + (size_t)b * 20480;
#pragma unroll
    for (int lt = 0; lt < 5; ++lt) {
        *(u16x4*)(ktb + (size_t)((cc0 >> 3) * LPn + lt * 16 + l15) * 8 + (cc0 & 7)) = cast4(ak[lt]);
        // v: D row = l (q4*4..+3), col = c (l15)
        *(u16x4*)(v + ((size_t)(b * Cn + c0 + l15)) * LKn + lt * 16 + q4 * 4) = cast4(av[lt]);
    }
    u16x4 z; z[0] = 0; z[1] = 0; z[2] = 0; z[3] = 0;
    *(u16x4*)(v + ((size_t)(b * Cn + c0 + l15)) * LKn + 80 + q4 * 4) = z;
}

// ---------------- 3: q projection with fused x transpose+cast staging ----------------
// 512 threads (8 waves x 32-o slice), 2 tiles of 64n, double-buffered LDS.
// Stage: read x[c][n] f32 coalesced -> cvt bf16 -> ds_write chunked (issue-early/write-late).
__launch_bounds__(512)
__global__ void k_gemm0(const u16* __restrict__ A, const float* __restrict__ x,
                        const float* __restrict__ bias, u16* __restrict__ qt) {
    int bx = blockIdx.x, b = blockIdx.y;
    int tid = threadIdx.x;
    int w = tid >> 6, lane = tid & 63;
    int l15 = lane & 15, q4 = lane >> 4;

    __shared__ __align__(16) u16 sB[2][64 * 256];   // 2 x 32KB chunk-ordered

    const float* xb = x + (size_t)b * Cn * Nn;
    int cs = tid >> 4;              // staging base c-row 0..31
    int ns = (tid & 15) * 4;        // staging n offset

    frag8 areg[2][8];
#pragma unroll
    for (int mt = 0; mt < 2; ++mt)
#pragma unroll
        for (int ks = 0; ks < 8; ++ks)
            areg[mt][ks] = *(const frag8*)(A + (size_t)((ks * 4 + q4) * 256 + w * 32 + mt * 16 + l15) * 8);
    f32x4 qb4[2];
#pragma unroll
    for (int mt = 0; mt < 2; ++mt)
        qb4[mt] = *(const f32x4*)(bias + w * 32 + mt * 16 + q4 * 4);

    f32x4 xr[8];
#define G0_LOADS(T)                                                                 \
    _Pragma("unroll")                                                               \
    for (int p = 0; p < 8; ++p)                                                     \
        xr[p] = *(const f32x4*)(xb + (size_t)(p * 32 + cs) * Nn + (T) * 64 + ns);
#define G0_WRITES(buf)                                                              \
    _Pragma("unroll")                                                               \
    for (int p = 0; p < 8; ++p) {                                                   \
        int c = p * 32 + cs;                                                        \
        u16* dst = &sB[buf][(size_t)((c >> 3) * 64) * 8 + (c & 7)];                 \
        _Pragma("unroll")                                                           \
        for (int j = 0; j < 4; ++j) dst[(ns + j) * 8] = f2b(xr[p][j]);              \
    }

    G0_LOADS(bx * 2)
    G0_WRITES(0)
    __syncthreads();
#pragma unroll
    for (int t = 0; t < 2; ++t) {
        if (t == 0) { G0_LOADS(bx * 2 + 1) }        // issue early; consumed after MFMA
        f32x4 acc[2][4];
#pragma unroll
        for (int i = 0; i < 2; ++i)
#pragma unroll
            for (int j = 0; j < 4; ++j) acc[i][j] = (f32x4){0.f, 0.f, 0.f, 0.f};
#pragma unroll
        for (int ks = 0; ks < 8; ++ks) {
            frag8 bf[4];
#pragma unroll
            for (int nt = 0; nt < 4; ++nt)
                bf[nt] = *(const frag8*)&sB[t][(size_t)((ks * 4 + q4) * 64 + nt * 16 + l15) * 8];
#pragma unroll
            for (int mt = 0; mt < 2; ++mt)
#pragma unroll
                for (int nt = 0; nt < 4; ++nt)
                    acc[mt][nt] = __builtin_amdgcn_mfma_f32_16x16x32_bf16(areg[mt][ks], bf[nt], acc[mt][nt], 0, 0, 0);
        }
        if (t == 0) { G0_WRITES(1) }
        // D row = o (q4*4+r), col = n (l15): chunked qt store
        u16* qtb = qt + ((size_t)(b * 64 + bx * 2 + t)) * 16384;
#pragma unroll
        for (int mt = 0; mt < 2; ++mt) {
            int o4 = w * 32 + mt * 16 + q4 * 4;
#pragma unroll
            for (int nt = 0; nt < 4; ++nt) {
                int row = nt * 16 + l15;
                u16x4 pk;
#pragma unroll
                for (int r = 0; r < 4; ++r) pk[r] = f2b(acc[mt][nt][r] + qb4[mt][r]);
                *(u16x4*)(qtb + (size_t)((o4 >> 3) * 64 + row) * 8 + (o4 & 7)) = pk;
            }
        }
        __syncthreads();
    }
#undef G0_LOADS
#undef G0_WRITES
}

// ---------------- 4: fused attention (8 waves, 128 n / block, kt in LDS) ----------------
__launch_bounds__(512)
__global__ void k_attn(const u16* __restrict__ ktc, const u16* __restrict__ v,
                       const u16* __restrict__ qt, u16* __restrict__ ht) {
    int nb = blockIdx.x, b = blockIdx.y;
    int tid = threadIdx.x;
    int w = tid >> 6, lane = tid & 63;
    int l15 = lane & 15, q4 = lane >> 4;

    __shared__ __align__(16) u16 skt[20480];        // 40KB chunked kt
    __shared__ u16 w_lds[8][16][104];               // per-wave softmax tiles

    const u16* ktb = ktc + (size_t)b * 20480;
    for (int c = tid; c < 2560; c += 512)
        gl16(ktb + (size_t)c * 8, &skt[(size_t)c * 8]);

    int T = nb * 2 + (w >> 2), rw = (w & 3) * 16;   // tile + row-base for this wave
    const u16* qtb = qt + ((size_t)(b * 64 + T)) * 16384;
    frag8 bq[8];
#pragma unroll
    for (int ks = 0; ks < 8; ++ks)
        bq[ks] = *(const frag8*)(qtb + (size_t)((ks * 4 + q4) * 64 + rw + l15) * 8);
    __syncthreads();

    f32x4 s[5];
#pragma unroll
    for (int mt = 0; mt < 5; ++mt) s[mt] = (f32x4){0.f, 0.f, 0.f, 0.f};
#pragma unroll
    for (int ks = 0; ks < 8; ++ks)
#pragma unroll
        for (int mt = 0; mt < 5; ++mt) {
            frag8 ak = *(const frag8*)&skt[(size_t)((ks * 4 + q4) * 80 + mt * 16 + l15) * 8];
            s[mt] = __builtin_amdgcn_mfma_f32_16x16x32_bf16(ak, bq[ks], s[mt], 0, 0, 0);
        }
    // lane: n = l15 (fixed), l = mt*16 + q4*4 + r. Softmax over l per n.
    float m = -3e38f;
#pragma unroll
    for (int mt = 0; mt < 5; ++mt)
#pragma unroll
        for (int r = 0; r < 4; ++r) {
            int l = mt * 16 + q4 * 4 + r;
            if (l < Ln) m = fmaxf(m, s[mt][r]);
        }
    m = fmaxf(m, __shfl_xor(m, 16));
    m = fmaxf(m, __shfl_xor(m, 32));
    float p[5][4];
    float sum = 0.f;
#pragma unroll
    for (int mt = 0; mt < 5; ++mt)
#pragma unroll
        for (int r = 0; r < 4; ++r) {
            int l = mt * 16 + q4 * 4 + r;
            float e = (l < Ln) ? __expf(s[mt][r] - m) : 0.f;
            p[mt][r] = e;
            sum += e;
        }
    sum += __shfl_xor(sum, 16);
    sum += __shfl_xor(sum, 32);
    float inv = 1.f / sum;

    // per-wave region: no cross-wave hazard, no barriers needed
    u32* wz = (u32*)&w_lds[w][0][0];                // 832 u32
#pragma unroll
    for (int i = 0; i < 13; ++i) wz[lane + i * 64] = 0;
#pragma unroll
    for (int mt = 0; mt < 5; ++mt)
#pragma unroll
        for (int r = 0; r < 4; ++r) {
            int l = mt * 16 + q4 * 4 + r;
            if (l < Ln) w_lds[w][l15][l] = f2b(p[mt][r] * inv);
        }

    frag8 aw[3];
#pragma unroll
    for (int ks = 0; ks < 3; ++ks)
        aw[ks] = *(const frag8*)(&w_lds[w][l15][ks * 32 + 8 * q4]);
    const u16* vb = v + (size_t)b * Cn * LKn;
    u16* hb = ht + ((size_t)(b * 64 + T)) * 16384;
#pragma unroll
    for (int ct = 0; ct < 16; ++ct) {
        f32x4 h = (f32x4){0.f, 0.f, 0.f, 0.f};
#pragma unroll
        for (int ks = 0; ks < 3; ++ks) {
            frag8 bv = *(const frag8*)(vb + (size_t)(ct * 16 + l15) * LKn + ks * 32 + 8 * q4);
            h = __builtin_amdgcn_mfma_f32_16x16x32_bf16(aw[ks], bv, h, 0, 0, 0);
        }
        int kc = ct * 2 + (l15 >> 3), off = l15 & 7;
#pragma unroll
        for (int r = 0; r < 4; ++r)
            hb[(size_t)(kc * 64 + rw + q4 * 4 + r) * 8 + off] = f2b(h[r]);
    }
}

// ---------------- 5: out projection + residual + fused GN partials ----------------
__launch_bounds__(512)
__global__ void k_gemm1(const u16* __restrict__ A, const u16* __restrict__ ht,
                        const float* __restrict__ bias, const float* __restrict__ xres,
                        u16* __restrict__ outp, float* __restrict__ gsum,
                        float* __restrict__ gsq) {
    int bx = blockIdx.x, b = blockIdx.y;
    int tid = threadIdx.x;
    int w = tid >> 6, lane = tid & 63;
    int l15 = lane & 15, q4 = lane >> 4;

    __shared__ __align__(16) u16 sB[2][64 * 256];   // 2 x 32KB

    frag8 areg[2][8];
#pragma unroll
    for (int mt = 0; mt < 2; ++mt)
#pragma unroll
        for (int ks = 0; ks < 8; ++ks)
            areg[mt][ks] = *(const frag8*)(A + (size_t)((ks * 4 + q4) * 256 + w * 32 + mt * 16 + l15) * 8);
    float obias[2], gps[2] = {0.f, 0.f}, gpq[2] = {0.f, 0.f};
#pragma unroll
    for (int mt = 0; mt < 2; ++mt) obias[mt] = bias[w * 32 + mt * 16 + l15];

#define G1_STAGE(buf, T)                                                            \
    {                                                                               \
        const u16* Bb = ht + ((size_t)(b * 64 + (T))) * 16384;                      \
        _Pragma("unroll")                                                           \
        for (int j = 0; j < 4; ++j) {                                               \
            int c = j * 512 + tid;                                                  \
            gl16(Bb + (size_t)c * 8, &sB[buf][(size_t)c * 8]);                      \
        }                                                                           \
    }

    G1_STAGE(0, bx * 2)
    __syncthreads();
#pragma unroll
    for (int t = 0; t < 2; ++t) {
        if (t == 0) { G1_STAGE(1, bx * 2 + 1) }
        f32x4 acc[4][2];
#pragma unroll
        for (int i = 0; i < 4; ++i)
#pragma unroll
            for (int j = 0; j < 2; ++j) acc[i][j] = (f32x4){0.f, 0.f, 0.f, 0.f};
#pragma unroll
        for (int ks = 0; ks < 8; ++ks) {
            frag8 bf[4];
#pragma unroll
            for (int nt = 0; nt < 4; ++nt)
                bf[nt] = *(const frag8*)&sB[t][(size_t)((ks * 4 + q4) * 64 + nt * 16 + l15) * 8];
#pragma unroll
            for (int nt = 0; nt < 4; ++nt)
#pragma unroll
                for (int mt = 0; mt < 2; ++mt)
                    acc[nt][mt] = __builtin_amdgcn_mfma_f32_16x16x32_bf16(bf[nt], areg[mt][ks], acc[nt][mt], 0, 0, 0);
        }
        // D row = n (q4*4+r), col = o (l15): t[o][n] + f32 residual + GN partials
#pragma unroll
        for (int mt = 0; mt < 2; ++mt) {
            int o = w * 32 + mt * 16 + l15;
#pragma unroll
            for (int nt = 0; nt < 4; ++nt) {
                int nb4 = (bx * 2 + t) * 64 + nt * 16 + q4 * 4;
                size_t rowb = ((size_t)(b * Cn + o)) * Nn + nb4;
                f32x4 xv = *(const f32x4*)(xres + rowb);
                u16x4 pk;
#pragma unroll
                for (int r = 0; r < 4; ++r) {
                    float val = acc[nt][mt][r] + obias[mt] + xv[r];
                    pk[r] = f2b(val);
                    gps[mt] += val; gpq[mt] += val * val;
                }
                *(u16x4*)(outp + rowb) = pk;
            }
        }
        __syncthreads();
    }
#undef G1_STAGE
#pragma unroll
    for (int mt = 0; mt < 2; ++mt) {
        float s = gps[mt], q = gpq[mt];
        s += __shfl_xor(s, 1);  q += __shfl_xor(q, 1);
        s += __shfl_xor(s, 2);  q += __shfl_xor(q, 2);
        s += __shfl_xor(s, 4);  q += __shfl_xor(q, 4);
        s += __shfl_xor(s, 16); q += __shfl_xor(q, 16);
        s += __shfl_xor(s, 32); q += __shfl_xor(q, 32);
        if ((lane & 55) == 0) {   // lane 0 or 8
            int g = (w * 32 + mt * 16 + (lane & 8)) >> 3;
            atomicAdd(&gsum[b * Gn + g], s);
            atomicAdd(&gsq[b * Gn + g], q);
        }
    }
}

// ---------------- 6: GroupNorm apply + Swish ----------------
__global__ void k_gnapply(const u16* __restrict__ t, const float* __restrict__ gsum,
                          const float* __restrict__ gsq, const float* __restrict__ gamma,
                          const float* __restrict__ beta, float* __restrict__ out) {
    int i = (blockIdx.x * 256 + threadIdx.x) * 4;
    int b = i >> 20;
    int rem = i & 1048575;
    int c = rem >> 12;
    int g = c >> 3;
    float mean = gsum[b * Gn + g] * (1.0f / 32768.f);
    float var = gsq[b * Gn + g] * (1.0f / 32768.f) - mean * mean;
    float rstd = rsqrtf(var + 1e-5f);
    float ga = gamma[c], be = beta[c];
    u16x4 tv = *(const u16x4*)(t + i);
    f32x4 o;
#pragma unroll
    for (int j = 0; j < 4; ++j) {
        float hv = (b2f(tv[j]) - mean) * rstd * ga + be;
        o[j] = hv / (1.f + __expf(-hv));
    }
    *(f32x4*)(out + i) = o;
}

// ---------------- launcher ----------------
extern "C" void kernel_launch(void* const* d_in, const int* in_sizes, int n_in,
                              void* d_out, int out_size, void* d_ws, size_t ws_size,
                              hipStream_t stream) {
    (void)in_sizes; (void)n_in; (void)out_size; (void)ws_size;
    const float* x     = (const float*)d_in[0];
    const float* ctx   = (const float*)d_in[1];
    const float* qw    = (const float*)d_in[2];
    const float* qb    = (const float*)d_in[3];
    const float* kw    = (const float*)d_in[4];
    const float* vw    = (const float*)d_in[5];
    const float* ow    = (const float*)d_in[6];
    const float* ob    = (const float*)d_in[7];
    const float* gamma = (const float*)d_in[8];
    const float* beta  = (const float*)d_in[9];
    float* out = (float*)d_out;
    char* ws = (char*)d_ws;

    u16* ht  = (u16*)(ws + OFF_HT);
    u16* qt  = (u16*)(ws + OFF_Q);
    u16* t   = (u16*)(ws + OFF_T);
    u16* ctxb = (u16*)(ws + OFF_CTXB);
    u16* kwb  = (u16*)(ws + OFF_KWB);
    u16* vwb  = (u16*)(ws + OFF_VWB);
    u16* kt  = (u16*)(ws + OFF_KT);
    u16* v   = (u16*)(ws + OFF_V);
    u16* qwb = (u16*)(ws + OFF_QWB);
    u16* owb = (u16*)(ws + OFF_OWB);
    float* gsum = (float*)(ws + OFF_GS);
    float* gsq  = (float*)(ws + OFF_GQ);

    hipMemsetAsync(ws + OFF_GS, 0, 4096, stream);   // gsum+gsq

    k_prep<<<1472, 256, 0, stream>>>(qw, ow, kw, vw, ctx, qwb, owb, kwb, vwb, ctxb);
    k_kv<<<dim3(4, Bn), 256, 0, stream>>>(kwb, vwb, ctxb, kt, v);
    k_gemm0<<<dim3(32, Bn), 512, 0, stream>>>(qwb, x, qb, qt);
    k_attn<<<dim3(32, Bn), 512, 0, stream>>>(kt, v, qt, ht);
    k_gemm1<<<dim3(32, Bn), 512, 0, stream>>>(owb, ht, ob, x, t, gsum, gsq);
    k_gnapply<<<16384, 256, 0, stream>>>(t, gsum, gsq, gamma, beta, out);
}

// Round 7
// 135.558 us; speedup vs baseline: 1.3989x; 1.0524x over previous
//
#include <hip/hip_runtime.h>
#include <cstdint>
#include <cstddef>

// ---------------- problem constants ----------------
#define Bn   16
#define Cn   256
#define Nn   4096      // 16^3 spatial
#define Ln   77
#define LPn  80        // padded L rows (scores), 5 tiles of 16
#define LKn  96        // padded L for PV K-dim (3 k-steps of 32)
#define CTXn 768
#define Gn   32

typedef unsigned short u16;
typedef unsigned int   u32;
using frag8 = __attribute__((ext_vector_type(8))) short;   // 8 x bf16 (4 VGPR)
using f32x4 = __attribute__((ext_vector_type(4))) float;
using u16x4 = __attribute__((ext_vector_type(4))) u16;
using u16x8 = __attribute__((ext_vector_type(8))) u16;

__device__ __forceinline__ float b2f(u16 b) {
    union { u32 u; float f; } v; v.u = ((u32)b) << 16; return v.f;
}
__device__ __forceinline__ u16 f2b(float f) {  // RNE f32->bf16
    union { float f; u32 u; } v; v.f = f;
    u32 u = v.u;
    return (u16)((u + 0x7fffu + ((u >> 16) & 1u)) >> 16);
}
__device__ __forceinline__ u16x4 cast4(f32x4 s) {
    u16x4 p; p[0] = f2b(s[0]); p[1] = f2b(s[1]); p[2] = f2b(s[2]); p[3] = f2b(s[3]);
    return p;
}
// async global->LDS, 16B per lane. LDS dest must be lane-linear (base + lane*16).
__device__ __forceinline__ void gl16(const u16* g, u16* l) {
    __builtin_amdgcn_global_load_lds((const __attribute__((address_space(1))) u32*)g,
                                     (__attribute__((address_space(3))) u32*)l, 16, 0, 0);
}

// Chunked activation layout: [b][ntile(64)][kc(32)][row(64)] of 16B chunks (8 ch).
// u16 index = (((b*64+nt)*2048) + kc*64 + row)*8 + (c&7),  kc=c>>3, row=n&63.
// Chunked weight layout: [kc(32)][row(256)]: u16 idx = ((k>>3)*256 + r)*8 + (k&7).
// Chunked kt layout:     [b][kc(32)][l(80)]: u16 idx = b*20480 + ((c>>3)*80 + l)*8 + (c&7).

// ---------------- ws layout (bytes) ----------------
static const size_t OFF_HT  = 0;                    // bf16 chunked [B][64][2048][8]
static const size_t OFF_Q   = 33554432;             // bf16 chunked (qt), later t (chunked)
static const size_t OFF_T   = 33554432;             // alias: qt dead after attn
static const size_t OFF_CTXB = 33554432;            // bf16 [16][80][768] (dead before gemm0)
static const size_t OFF_KWB  = 35520512;            // bf16 [256][768]
static const size_t OFF_VWB  = 35913728;            // bf16 [256][768]
static const size_t OFF_KT  = 67108864;             // bf16 chunked [B][32][80][8] (40KB/b)
static const size_t OFF_V   = 67764224;             // bf16 [B][256][96]
static const size_t OFF_QWB = 68550656;             // bf16 chunked [32][256][8]
static const size_t OFF_OWB = 68681728;             // bf16 chunked [32][256][8]
static const size_t OFF_GS  = 68812800;             // f32 [B][32]
static const size_t OFF_GQ  = 68814848;             // f32 [B][32]
// xbt (bf16 chunked copy of x, 32MB) lives in d_out (fully overwritten by gnapply)

// ---------------- 1: cast to bf16 (qw/ow chunked) + zero GN accumulators ----------------
__global__ void k_prep(const float* __restrict__ qw, const float* __restrict__ ow,
                       const float* __restrict__ kw, const float* __restrict__ vw,
                       const float* __restrict__ ctx,
                       u16* __restrict__ qwb, u16* __restrict__ owb,
                       u16* __restrict__ kwb, u16* __restrict__ vwb,
                       u16* __restrict__ ctxb, float* __restrict__ gz) {
    int i = blockIdx.x * 256 + threadIdx.x;        // 376832 total
    if (i < 1024) gz[i] = 0.f;                     // gsum+gsq (4KB, contiguous)
    if (i < 16384) {
        int e = i * 4; int r = e >> 8; int k = e & 255;
        *(u16x4*)(qwb + ((size_t)((k >> 3) * 256 + r) * 8 + (k & 7))) =
            cast4(*(const f32x4*)(qw + e));
    } else if (i < 32768) {
        int e = (i - 16384) * 4; int r = e >> 8; int k = e & 255;
        *(u16x4*)(owb + ((size_t)((k >> 3) * 256 + r) * 8 + (k & 7))) =
            cast4(*(const f32x4*)(ow + e));
    } else if (i < 81920) {
        int j = i - 32768;
        *(u16x4*)(kwb + j * 4) = cast4(*(const f32x4*)(kw + j * 4));
    } else if (i < 131072) {
        int j = i - 81920;
        *(u16x4*)(vwb + j * 4) = cast4(*(const f32x4*)(vw + j * 4));
    } else {
        int j = i - 131072;                        // 0..245759
        int e = j * 4;
        int row = e / CTXn;                        // b*80 + l
        int d = e - row * CTXn;
        int b = row / LPn, l = row - b * LPn;
        u16x4 pk;
        if (l < Ln) {
            pk = cast4(*(const f32x4*)(ctx + ((size_t)(b * Ln + l)) * CTXn + d));
        } else {
            pk[0] = 0; pk[1] = 0; pk[2] = 0; pk[3] = 0;
        }
        *(u16x4*)(ctxb + e) = pk;
    }
}

// ---------------- 2: k/v projections via MFMA (kt stored chunked) ----------------
__launch_bounds__(256)
__global__ void k_kv(const u16* __restrict__ kwb, const u16* __restrict__ vwb,
                     const u16* __restrict__ ctxb, u16* __restrict__ kt,
                     u16* __restrict__ v) {
    int b = blockIdx.y;
    int tid = threadIdx.x;
    int wave = tid >> 6, lane = tid & 63;
    int l15 = lane & 15, q4 = lane >> 4;
    int c0 = blockIdx.x * 64 + wave * 16;
    const u16* cb = ctxb + (size_t)b * LPn * CTXn;

    f32x4 ak[5], av[5];
#pragma unroll
    for (int lt = 0; lt < 5; ++lt) {
        ak[lt] = (f32x4){0.f, 0.f, 0.f, 0.f};
        av[lt] = (f32x4){0.f, 0.f, 0.f, 0.f};
    }
    for (int ks = 0; ks < CTXn / 32; ++ks) {
        int kk = ks * 32 + 8 * q4;
        frag8 fk = *(const frag8*)(kwb + (size_t)(c0 + l15) * CTXn + kk);
        frag8 fv = *(const frag8*)(vwb + (size_t)(c0 + l15) * CTXn + kk);
#pragma unroll
        for (int lt = 0; lt < 5; ++lt) {
            frag8 fc = *(const frag8*)(cb + (size_t)(lt * 16 + l15) * CTXn + kk);
            ak[lt] = __builtin_amdgcn_mfma_f32_16x16x32_bf16(fk, fc, ak[lt], 0, 0, 0);
            av[lt] = __builtin_amdgcn_mfma_f32_16x16x32_bf16(fc, fv, av[lt], 0, 0, 0);
        }
    }
    // kt chunked: D row = c (q4*4..+3), col = l (l15)
    int cc0 = c0 + q4 * 4;
    u16* ktb = kt + (size_t)b * 20480;
#pragma unroll
    for (int lt = 0; lt < 5; ++lt) {
        *(u16x4*)(ktb + (size_t)((cc0 >> 3) * LPn + lt * 16 + l15) * 8 + (cc0 & 7)) = cast4(ak[lt]);
        // v: D row = l (q4*4..+3), col = c (l15)
        *(u16x4*)(v + ((size_t)(b * Cn + c0 + l15)) * LKn + lt * 16 + q4 * 4) = cast4(av[lt]);
    }
    u16x4 z; z[0] = 0; z[1] = 0; z[2] = 0; z[3] = 0;
    *(u16x4*)(v + ((size_t)(b * Cn + c0 + l15)) * LKn + 80 + q4 * 4) = z;
}

// ---------------- 3: q projection + fused x transpose/cast + xbt emission ----------------
// 512 threads (8 waves x 32-o slice), 2 tiles of 64n, double-buffered LDS.
__launch_bounds__(512)
__global__ void k_gemm0(const u16* __restrict__ A, const float* __restrict__ x,
                        const float* __restrict__ bias, u16* __restrict__ qt,
                        u16* __restrict__ xbt) {
    int bx = blockIdx.x, b = blockIdx.y;
    int tid = threadIdx.x;
    int w = tid >> 6, lane = tid & 63;
    int l15 = lane & 15, q4 = lane >> 4;

    __shared__ __align__(16) u16 sB[2][64 * 256];   // 2 x 32KB chunk-ordered

    const float* xb = x + (size_t)b * Cn * Nn;
    int cs = tid >> 4;              // staging base c-row 0..31
    int ns = (tid & 15) * 4;        // staging n offset

    frag8 areg[2][8];
#pragma unroll
    for (int mt = 0; mt < 2; ++mt)
#pragma unroll
        for (int ks = 0; ks < 8; ++ks)
            areg[mt][ks] = *(const frag8*)(A + (size_t)((ks * 4 + q4) * 256 + w * 32 + mt * 16 + l15) * 8);
    f32x4 qb4[2];
#pragma unroll
    for (int mt = 0; mt < 2; ++mt)
        qb4[mt] = *(const f32x4*)(bias + w * 32 + mt * 16 + q4 * 4);

    f32x4 xr[8];
#define G0_LOADS(T)                                                                 \
    _Pragma("unroll")                                                               \
    for (int p = 0; p < 8; ++p)                                                     \
        xr[p] = *(const f32x4*)(xb + (size_t)(p * 32 + cs) * Nn + (T) * 64 + ns);
#define G0_WRITES(buf)                                                              \
    _Pragma("unroll")                                                               \
    for (int p = 0; p < 8; ++p) {                                                   \
        int c = p * 32 + cs;                                                        \
        u16* dst = &sB[buf][(size_t)((c >> 3) * 64) * 8 + (c & 7)];                 \
        _Pragma("unroll")                                                           \
        for (int j = 0; j < 4; ++j) dst[(ns + j) * 8] = f2b(xr[p][j]);              \
    }

    G0_LOADS(bx * 2)
    G0_WRITES(0)
    __syncthreads();
#pragma unroll
    for (int t = 0; t < 2; ++t) {
        // dump the finished bf16 x tile to xbt (coalesced; residual for gemm1)
        u16* xd = xbt + ((size_t)(b * 64 + bx * 2 + t)) * 16384;
#pragma unroll
        for (int j = 0; j < 4; ++j) {
            int c = j * 512 + tid;
            *(u16x8*)(xd + (size_t)c * 8) = *(const u16x8*)&sB[t][(size_t)c * 8];
        }
        if (t == 0) { G0_LOADS(bx * 2 + 1) }        // issue early; consumed after MFMA
        f32x4 acc[2][4];
#pragma unroll
        for (int i = 0; i < 2; ++i)
#pragma unroll
            for (int j = 0; j < 4; ++j) acc[i][j] = (f32x4){0.f, 0.f, 0.f, 0.f};
#pragma unroll
        for (int ks = 0; ks < 8; ++ks) {
            frag8 bf[4];
#pragma unroll
            for (int nt = 0; nt < 4; ++nt)
                bf[nt] = *(const frag8*)&sB[t][(size_t)((ks * 4 + q4) * 64 + nt * 16 + l15) * 8];
#pragma unroll
            for (int mt = 0; mt < 2; ++mt)
#pragma unroll
                for (int nt = 0; nt < 4; ++nt)
                    acc[mt][nt] = __builtin_amdgcn_mfma_f32_16x16x32_bf16(areg[mt][ks], bf[nt], acc[mt][nt], 0, 0, 0);
        }
        if (t == 0) { G0_WRITES(1) }
        // D row = o (q4*4+r), col = n (l15): chunked qt store
        u16* qtb = qt + ((size_t)(b * 64 + bx * 2 + t)) * 16384;
#pragma unroll
        for (int mt = 0; mt < 2; ++mt) {
            int o4 = w * 32 + mt * 16 + q4 * 4;
#pragma unroll
            for (int nt = 0; nt < 4; ++nt) {
                int row = nt * 16 + l15;
                u16x4 pk;
#pragma unroll
                for (int r = 0; r < 4; ++r) pk[r] = f2b(acc[mt][nt][r] + qb4[mt][r]);
                *(u16x4*)(qtb + (size_t)((o4 >> 3) * 64 + row) * 8 + (o4 & 7)) = pk;
            }
        }
        __syncthreads();
    }
#undef G0_LOADS
#undef G0_WRITES
}

// ---------------- 4: fused attention (8 waves, 128 n / block, kt in LDS) ----------------
__launch_bounds__(512)
__global__ void k_attn(const u16* __restrict__ ktc, const u16* __restrict__ v,
                       const u16* __restrict__ qt, u16* __restrict__ ht) {
    int nb = blockIdx.x, b = blockIdx.y;
    int tid = threadIdx.x;
    int w = tid >> 6, lane = tid & 63;
    int l15 = lane & 15, q4 = lane >> 4;

    __shared__ __align__(16) u16 skt[20480];        // 40KB chunked kt
    __shared__ u16 w_lds[8][16][104];               // per-wave softmax tiles

    const u16* ktb = ktc + (size_t)b * 20480;
    for (int c = tid; c < 2560; c += 512)
        gl16(ktb + (size_t)c * 8, &skt[(size_t)c * 8]);

    int T = nb * 2 + (w >> 2), rw = (w & 3) * 16;   // tile + row-base for this wave
    const u16* qtb = qt + ((size_t)(b * 64 + T)) * 16384;
    frag8 bq[8];
#pragma unroll
    for (int ks = 0; ks < 8; ++ks)
        bq[ks] = *(const frag8*)(qtb + (size_t)((ks * 4 + q4) * 64 + rw + l15) * 8);
    __syncthreads();

    f32x4 s[5];
#pragma unroll
    for (int mt = 0; mt < 5; ++mt) s[mt] = (f32x4){0.f, 0.f, 0.f, 0.f};
#pragma unroll
    for (int ks = 0; ks < 8; ++ks)
#pragma unroll
        for (int mt = 0; mt < 5; ++mt) {
            frag8 ak = *(const frag8*)&skt[(size_t)((ks * 4 + q4) * 80 + mt * 16 + l15) * 8];
            s[mt] = __builtin_amdgcn_mfma_f32_16x16x32_bf16(ak, bq[ks], s[mt], 0, 0, 0);
        }
    // lane: n = l15 (fixed), l = mt*16 + q4*4 + r. Softmax over l per n.
    float m = -3e38f;
#pragma unroll
    for (int mt = 0; mt < 5; ++mt)
#pragma unroll
        for (int r = 0; r < 4; ++r) {
            int l = mt * 16 + q4 * 4 + r;
            if (l < Ln) m = fmaxf(m, s[mt][r]);
        }
    m = fmaxf(m, __shfl_xor(m, 16));
    m = fmaxf(m, __shfl_xor(m, 32));
    float p[5][4];
    float sum = 0.f;
#pragma unroll
    for (int mt = 0; mt < 5; ++mt)
#pragma unroll
        for (int r = 0; r < 4; ++r) {
            int l = mt * 16 + q4 * 4 + r;
            float e = (l < Ln) ? __expf(s[mt][r] - m) : 0.f;
            p[mt][r] = e;
            sum += e;
        }
    sum += __shfl_xor(sum, 16);
    sum += __shfl_xor(sum, 32);
    float inv = 1.f / sum;

    // per-wave region: no cross-wave hazard, no barriers needed
    u32* wz = (u32*)&w_lds[w][0][0];                // 832 u32
#pragma unroll
    for (int i = 0; i < 13; ++i) wz[lane + i * 64] = 0;
#pragma unroll
    for (int mt = 0; mt < 5; ++mt)
#pragma unroll
        for (int r = 0; r < 4; ++r) {
            int l = mt * 16 + q4 * 4 + r;
            if (l < Ln) w_lds[w][l15][l] = f2b(p[mt][r] * inv);
        }

    frag8 aw[3];
#pragma unroll
    for (int ks = 0; ks < 3; ++ks)
        aw[ks] = *(const frag8*)(&w_lds[w][l15][ks * 32 + 8 * q4]);
    const u16* vb = v + (size_t)b * Cn * LKn;
    u16* hb = ht + ((size_t)(b * 64 + T)) * 16384;
#pragma unroll
    for (int ct = 0; ct < 16; ++ct) {
        f32x4 h = (f32x4){0.f, 0.f, 0.f, 0.f};
#pragma unroll
        for (int ks = 0; ks < 3; ++ks) {
            frag8 bv = *(const frag8*)(vb + (size_t)(ct * 16 + l15) * LKn + ks * 32 + 8 * q4);
            h = __builtin_amdgcn_mfma_f32_16x16x32_bf16(aw[ks], bv, h, 0, 0, 0);
        }
        int kc = ct * 2 + (l15 >> 3), off = l15 & 7;
#pragma unroll
        for (int r = 0; r < 4; ++r)
            hb[(size_t)(kc * 64 + rw + q4 * 4 + r) * 8 + off] = f2b(h[r]);
    }
}

// ---------------- 5: out projection + bf16 residual + fused GN partials ----------------
// Unswapped: D row = o, col = n. t stored CHUNKED; residual read from xbt (chunked bf16).
__launch_bounds__(512)
__global__ void k_gemm1(const u16* __restrict__ A, const u16* __restrict__ ht,
                        const float* __restrict__ bias, const u16* __restrict__ xbt,
                        u16* __restrict__ outp, float* __restrict__ gsum,
                        float* __restrict__ gsq) {
    int bx = blockIdx.x, b = blockIdx.y;
    int tid = threadIdx.x;
    int w = tid >> 6, lane = tid & 63;
    int l15 = lane & 15, q4 = lane >> 4;

    __shared__ __align__(16) u16 sB[2][64 * 256];   // 2 x 32KB

    frag8 areg[2][8];
#pragma unroll
    for (int mt = 0; mt < 2; ++mt)
#pragma unroll
        for (int ks = 0; ks < 8; ++ks)
            areg[mt][ks] = *(const frag8*)(A + (size_t)((ks * 4 + q4) * 256 + w * 32 + mt * 16 + l15) * 8);
    f32x4 ob4[2];
    float gps[2] = {0.f, 0.f}, gpq[2] = {0.f, 0.f};
#pragma unroll
    for (int mt = 0; mt < 2; ++mt)
        ob4[mt] = *(const f32x4*)(bias + w * 32 + mt * 16 + q4 * 4);

#define G1_STAGE(buf, T)                                                            \
    {                                                                               \
        const u16* Bb = ht + ((size_t)(b * 64 + (T))) * 16384;                      \
        _Pragma("unroll")                                                           \
        for (int j = 0; j < 4; ++j) {                                               \
            int c = j * 512 + tid;                                                  \
            gl16(Bb + (size_t)c * 8, &sB[buf][(size_t)c * 8]);                      \
        }                                                                           \
    }

    G1_STAGE(0, bx * 2)
    __syncthreads();
#pragma unroll
    for (int t = 0; t < 2; ++t) {
        if (t == 0) { G1_STAGE(1, bx * 2 + 1) }
        f32x4 acc[2][4];
#pragma unroll
        for (int i = 0; i < 2; ++i)
#pragma unroll
            for (int j = 0; j < 4; ++j) acc[i][j] = (f32x4){0.f, 0.f, 0.f, 0.f};
#pragma unroll
        for (int ks = 0; ks < 8; ++ks) {
            frag8 bf[4];
#pragma unroll
            for (int nt = 0; nt < 4; ++nt)
                bf[nt] = *(const frag8*)&sB[t][(size_t)((ks * 4 + q4) * 64 + nt * 16 + l15) * 8];
#pragma unroll
            for (int mt = 0; mt < 2; ++mt)
#pragma unroll
                for (int nt = 0; nt < 4; ++nt)
                    acc[mt][nt] = __builtin_amdgcn_mfma_f32_16x16x32_bf16(areg[mt][ks], bf[nt], acc[mt][nt], 0, 0, 0);
        }
        // D row = o (q4*4+r), col = n (l15). Chunked t store + chunked residual.
        size_t tbase = ((size_t)(b * 64 + bx * 2 + t)) * 16384;
        u16* tb = outp + tbase;
        const u16* xd = xbt + tbase;
#pragma unroll
        for (int mt = 0; mt < 2; ++mt) {
            int o4 = w * 32 + mt * 16 + q4 * 4;
            size_t kcb = (size_t)(o4 >> 3) * 64;
            int off = o4 & 7;
#pragma unroll
            for (int nt = 0; nt < 4; ++nt) {
                int rown = nt * 16 + l15;
                size_t idx = (kcb + rown) * 8 + off;
                u16x4 xv = *(const u16x4*)(xd + idx);
                u16x4 pk;
#pragma unroll
                for (int r = 0; r < 4; ++r) {
                    float val = acc[mt][nt][r] + ob4[mt][r] + b2f(xv[r]);
                    pk[r] = f2b(val);
                    gps[mt] += val; gpq[mt] += val * val;
                }
                *(u16x4*)(tb + idx) = pk;
            }
        }
        __syncthreads();
    }
#undef G1_STAGE
    // GN reduce: lane's 4 vals all in group g = w*4 + mt*2 + (q4>>1)
#pragma unroll
    for (int mt = 0; mt < 2; ++mt) {
        float s = gps[mt], q = gpq[mt];
        s += __shfl_xor(s, 1);  q += __shfl_xor(q, 1);
        s += __shfl_xor(s, 2);  q += __shfl_xor(q, 2);
        s += __shfl_xor(s, 4);  q += __shfl_xor(q, 4);
        s += __shfl_xor(s, 8);  q += __shfl_xor(q, 8);
        s += __shfl_xor(s, 16); q += __shfl_xor(q, 16);
        if ((lane & 31) == 0) {   // lane 0 (q4 pair 0/1) or lane 32 (q4 pair 2/3)
            int g = w * 4 + mt * 2 + (lane >> 5);
            atomicAdd(&gsum[b * Gn + g], s);
            atomicAdd(&gsq[b * Gn + g], q);
        }
    }
}

// ---------------- 6: GroupNorm apply + Swish (chunked t -> [b][c][n] f32 out) ----------------
__launch_bounds__(256)
__global__ void k_gnapply(const u16* __restrict__ t, const float* __restrict__ gsum,
                          const float* __restrict__ gsq, const float* __restrict__ gamma,
                          const float* __restrict__ beta, float* __restrict__ out) {
    int nt = blockIdx.x, b = blockIdx.y;
    __shared__ __align__(16) u16 s[16384];          // 32KB tile
    const u16* tb = t + ((size_t)(b * 64 + nt)) * 16384;
    int tid = threadIdx.x;
#pragma unroll
    for (int j = 0; j < 8; ++j) {
        int c = j * 256 + tid;
        gl16(tb + (size_t)c * 8, &s[(size_t)c * 8]);
    }
    int c8 = tid >> 3, n8 = tid & 7;                // group g = c8, n-base = n8*8
    float mean = gsum[b * Gn + c8] * (1.0f / 32768.f);
    float var = gsq[b * Gn + c8] * (1.0f / 32768.f) - mean * mean;
    float rstd = rsqrtf(var + 1e-5f);
    __syncthreads();
    u16x8 v[8];
#pragma unroll
    for (int j = 0; j < 8; ++j)
        v[j] = *(const u16x8*)&s[(size_t)(c8 * 64 + n8 * 8 + j) * 8];
    float* ob = out + ((size_t)(b * Cn + c8 * 8)) * Nn + nt * 64 + n8 * 8;
#pragma unroll
    for (int cc = 0; cc < 8; ++cc) {
        float ga = gamma[c8 * 8 + cc], be = beta[c8 * 8 + cc];
        f32x4 lo, hi;
#pragma unroll
        for (int j = 0; j < 4; ++j) {
            float hv = (b2f(v[j][cc]) - mean) * rstd * ga + be;
            lo[j] = hv / (1.f + __expf(-hv));
        }
#pragma unroll
        for (int j = 0; j < 4; ++j) {
            float hv = (b2f(v[j + 4][cc]) - mean) * rstd * ga + be;
            hi[j] = hv / (1.f + __expf(-hv));
        }
        *(f32x4*)(ob + (size_t)cc * Nn) = lo;
        *(f32x4*)(ob + (size_t)cc * Nn + 4) = hi;
    }
}

// ---------------- launcher ----------------
extern "C" void kernel_launch(void* const* d_in, const int* in_sizes, int n_in,
                              void* d_out, int out_size, void* d_ws, size_t ws_size,
                              hipStream_t stream) {
    (void)in_sizes; (void)n_in; (void)out_size; (void)ws_size;
    const float* x     = (const float*)d_in[0];
    const float* ctx   = (const float*)d_in[1];
    const float* qw    = (const float*)d_in[2];
    const float* qb    = (const float*)d_in[3];
    const float* kw    = (const float*)d_in[4];
    const float* vw    = (const float*)d_in[5];
    const float* ow    = (const float*)d_in[6];
    const float* ob    = (const float*)d_in[7];
    const float* gamma = (const float*)d_in[8];
    const float* beta  = (const float*)d_in[9];
    float* out = (float*)d_out;
    char* ws = (char*)d_ws;

    u16* ht  = (u16*)(ws + OFF_HT);
    u16* qt  = (u16*)(ws + OFF_Q);
    u16* t   = (u16*)(ws + OFF_T);
    u16* ctxb = (u16*)(ws + OFF_CTXB);
    u16* kwb  = (u16*)(ws + OFF_KWB);
    u16* vwb  = (u16*)(ws + OFF_VWB);
    u16* kt  = (u16*)(ws + OFF_KT);
    u16* v   = (u16*)(ws + OFF_V);
    u16* qwb = (u16*)(ws + OFF_QWB);
    u16* owb = (u16*)(ws + OFF_OWB);
    float* gsum = (float*)(ws + OFF_GS);
    float* gsq  = (float*)(ws + OFF_GQ);
    u16* xbt = (u16*)d_out;           // 32MB scratch inside out (overwritten by gnapply)

    k_prep<<<1472, 256, 0, stream>>>(qw, ow, kw, vw, ctx, qwb, owb, kwb, vwb, ctxb, gsum);
    k_kv<<<dim3(4, Bn), 256, 0, stream>>>(kwb, vwb, ctxb, kt, v);
    k_gemm0<<<dim3(32, Bn), 512, 0, stream>>>(qwb, x, qb, qt, xbt);
    k_attn<<<dim3(32, Bn), 512, 0, stream>>>(kt, v, qt, ht);
    k_gemm1<<<dim3(32, Bn), 512, 0, stream>>>(owb, ht, ob, xbt, t, gsum, gsq);
    k_gnapply<<<dim3(64, Bn), 256, 0, stream>>>(t, gsum, gsq, gamma, beta, out);
}